// Round 2
// baseline (19150.812 us; speedup 1.0000x reference)
//
#include <hip/hip_runtime.h>
#include <cmath>

constexpr int B = 256, T = 1024, D = 128, H = 256, NC = 10;
constexpr int K = D + H;                          // 384

// ws layout (in floats):
//   cst   [H][B]            @ 0          (c state, transposed)
//   hbuf  [2][H][B]         @ HBUF_OFF   (h ping-pong, transposed)
//   wrep  [64][K][16]       @ WREP_OFF   (per-col-block weight slices, k-major)
constexpr size_t CST_OFF  = 0;
constexpr size_t HBUF_OFF = (size_t)H * B;               // 65536
constexpr size_t WREP_OFF = HBUF_OFF + 2ull * H * B;     // 196608
constexpr size_t WREP_ELEMS = 64ull * K * 16;            // 393216

__device__ __forceinline__ float fast_sig(float x) { return 1.f / (1.f + __expf(-x)); }
__device__ __forceinline__ float fast_tanh(float x) {
  float ax = fabsf(x);
  float e = __expf(2.f * ax);            // overflow -> inf -> r -> 1, safe
  float r = 1.f - 2.f / (e + 1.f);
  return copysignf(r, x);
}

// One-time: zero c and h0; repack weights into wrep[cb][k][g*4+jj].
__global__ void setup_kernel(const float* __restrict__ wgx, const float* __restrict__ wgh,
                             const float* __restrict__ wix, const float* __restrict__ wih,
                             const float* __restrict__ wfx, const float* __restrict__ wfh,
                             const float* __restrict__ wox, const float* __restrict__ woh,
                             float* __restrict__ ws) {
  int idx = blockIdx.x * blockDim.x + threadIdx.x;       // 0 .. 393215
  if (idx < (int)(H * B)) {
    ws[CST_OFF + idx]  = 0.f;                            // c_0 = 0
    ws[HBUF_OFF + idx] = 0.f;                            // h_0 = 0 (buffer 0)
  }
  const float* wxs[4] = {wgx, wix, wfx, wox};
  const float* whs[4] = {wgh, wih, wfh, woh};
  int c  = idx & 15;
  int r  = (idx >> 4) % K;
  int cb = idx / (K * 16);
  int g  = c >> 2, jj = c & 3;
  int j  = cb * 4 + jj;
  float v = (r < D) ? wxs[g][r * H + j] : whs[g][(r - D) * H + j];
  ws[WREP_OFF + idx] = v;
}

#define FMA16(a, wptr) { \
  const float4* _wv = (const float4*)(wptr); \
  float4 w0 = _wv[0], w1 = _wv[1], w2 = _wv[2], w3 = _wv[3]; \
  acc[0]  += (a) * w0.x; acc[1]  += (a) * w0.y; acc[2]  += (a) * w0.z; acc[3]  += (a) * w0.w; \
  acc[4]  += (a) * w1.x; acc[5]  += (a) * w1.y; acc[6]  += (a) * w1.z; acc[7]  += (a) * w1.w; \
  acc[8]  += (a) * w2.x; acc[9]  += (a) * w2.y; acc[10] += (a) * w2.z; acc[11] += (a) * w2.w; \
  acc[12] += (a) * w3.x; acc[13] += (a) * w3.y; acc[14] += (a) * w3.z; acc[15] += (a) * w3.w; }

// One time step. Grid 256 = 4 batch-quarters x 64 col-blocks; 256 threads = 4 waves.
// Wave = K-split group; lane = local batch index. Each thread: acc over 16 gate cols.
__launch_bounds__(256, 1)
__global__ void lstm_step(const float* __restrict__ x,
                          const float* __restrict__ bg, const float* __restrict__ bi,
                          const float* __restrict__ bf, const float* __restrict__ bo,
                          float* __restrict__ ws, int t) {
  __shared__ float A[128][64];                 // 32 KB h-stage; epilogue aliases as Zp
  float* Zp = &A[0][0];                        // Zp[w][c][64]: 4096 floats <= 8192

  const float* hread  = ws + HBUF_OFF + (size_t)(t & 1) * (H * B);
  float*       hwrite = ws + HBUF_OFF + (size_t)((t + 1) & 1) * (H * B);
  float*       cst    = ws + CST_OFF;
  const float* wrep   = ws + WREP_OFF;

  const int bq = blockIdx.x >> 6;
  const int cb = blockIdx.x & 63;
  const int b0 = bq * 64;
  const int j0 = cb * 4;
  const int t_ = threadIdx.x;
  const int w = t_ >> 6, lane = t_ & 63;
  const float* wslice = wrep + (size_t)cb * (K * 16);

  // ---- issue all global loads up front (x rows, h-lo, h-hi) ----
  const float* xb = x + ((size_t)(b0 + lane) * T + t) * D + w * 32;
  float4 xr[8];
  #pragma unroll
  for (int i = 0; i < 8; ++i) xr[i] = ((const float4*)xb)[i];

  float4 hlo[8], hhi[8];
  #pragma unroll
  for (int i = 0; i < 8; ++i) {
    int fid = t_ + i * 256;                    // 0..2047
    int r = fid >> 4, b4 = (fid & 15) << 2;
    hlo[i] = *(const float4*)(hread + (size_t)r * B + b0 + b4);
    hhi[i] = *(const float4*)(hread + (size_t)(128 + r) * B + b0 + b4);
  }

  float acc[16];
  #pragma unroll
  for (int c = 0; c < 16; ++c) acc[c] = 0.f;

  // ---- phase 0: h rows 0..127 ----
  #pragma unroll
  for (int i = 0; i < 8; ++i) {
    int fid = t_ + i * 256;
    int r = fid >> 4, b4 = (fid & 15) << 2;
    *(float4*)&A[r][b4] = hlo[i];
  }
  __syncthreads();
  {
    const float* wk = wslice + (size_t)(D + w * 32) * 16;
    #pragma unroll 8
    for (int kk = 0; kk < 32; ++kk) {
      float a = A[w * 32 + kk][lane];
      FMA16(a, wk + kk * 16);
    }
  }
  // ---- x contribution from registers (k rows w*32 .. w*32+31) ----
  {
    const float* wk = wslice + (size_t)(w * 32) * 16;
    #pragma unroll
    for (int i = 0; i < 8; ++i) {
      FMA16(xr[i].x, wk + (i * 4 + 0) * 16);
      FMA16(xr[i].y, wk + (i * 4 + 1) * 16);
      FMA16(xr[i].z, wk + (i * 4 + 2) * 16);
      FMA16(xr[i].w, wk + (i * 4 + 3) * 16);
    }
  }
  __syncthreads();

  // ---- phase 1: h rows 128..255 (data already in registers) ----
  #pragma unroll
  for (int i = 0; i < 8; ++i) {
    int fid = t_ + i * 256;
    int r = fid >> 4, b4 = (fid & 15) << 2;
    *(float4*)&A[r][b4] = hhi[i];
  }
  __syncthreads();
  {
    const float* wk = wslice + (size_t)(D + 128 + w * 32) * 16;
    #pragma unroll 8
    for (int kk = 0; kk < 32; ++kk) {
      float a = A[w * 32 + kk][lane];
      FMA16(a, wk + kk * 16);
    }
  }
  __syncthreads();

  // ---- K-split partial exchange via LDS (aliases A) ----
  #pragma unroll
  for (int c = 0; c < 16; ++c) Zp[(w * 16 + c) * 64 + lane] = acc[c];
  __syncthreads();

  // ---- epilogue: thread owns (h col j0+w, batch b0+lane) ----
  float z0 = 0.f, z1 = 0.f, z2 = 0.f, z3 = 0.f;
  #pragma unroll
  for (int ww = 0; ww < 4; ++ww) {
    z0 += Zp[(ww * 16 + 0 * 4 + w) * 64 + lane];
    z1 += Zp[(ww * 16 + 1 * 4 + w) * 64 + lane];
    z2 += Zp[(ww * 16 + 2 * 4 + w) * 64 + lane];
    z3 += Zp[(ww * 16 + 3 * 4 + w) * 64 + lane];
  }
  const int jglob = j0 + w;
  const size_t cidx = (size_t)jglob * B + b0 + lane;
  float gg = fast_tanh(z0 + bg[jglob]);
  float ii = fast_sig (z1 + bi[jglob]);
  float ff = fast_sig (z2 + bf[jglob]);
  float oo = fast_sig (z3 + bo[jglob]);
  float cn = gg * ii + cst[cidx] * ff;
  cst[cidx] = cn;
  hwrite[cidx] = fast_tanh(cn) * oo;
}

// out[b][c] = sum_j h[j][b] * wph[j][c] + bp[c]
__global__ void proj_kernel(const float* __restrict__ hT, const float* __restrict__ wph,
                            const float* __restrict__ bp, float* __restrict__ out) {
  int b = blockIdx.x;
  int j = threadIdx.x;
  float hv = hT[(size_t)j * B + b];
  float p[NC];
  #pragma unroll
  for (int c = 0; c < NC; ++c) p[c] = hv * wph[j * NC + c];
  #pragma unroll
  for (int off = 32; off >= 1; off >>= 1)
    #pragma unroll
    for (int c = 0; c < NC; ++c) p[c] += __shfl_xor(p[c], off, 64);
  __shared__ float s[NC];
  if (threadIdx.x < NC) s[threadIdx.x] = 0.f;
  __syncthreads();
  if ((threadIdx.x & 63) == 0)
    for (int c = 0; c < NC; ++c) atomicAdd(&s[c], p[c]);
  __syncthreads();
  if (j < NC) out[b * NC + j] = s[j] + bp[j];
}

extern "C" void kernel_launch(void* const* d_in, const int* in_sizes, int n_in,
                              void* d_out, int out_size, void* d_ws, size_t ws_size,
                              hipStream_t stream) {
  const float* x   = (const float*)d_in[0];
  const float* wgx = (const float*)d_in[1];
  const float* wgh = (const float*)d_in[2];
  const float* bg  = (const float*)d_in[3];
  const float* wix = (const float*)d_in[4];
  const float* wih = (const float*)d_in[5];
  const float* bi  = (const float*)d_in[6];
  const float* wfx = (const float*)d_in[7];
  const float* wfh = (const float*)d_in[8];
  const float* bf  = (const float*)d_in[9];
  const float* wox = (const float*)d_in[10];
  const float* woh = (const float*)d_in[11];
  const float* bo  = (const float*)d_in[12];
  const float* wph = (const float*)d_in[13];
  const float* bp  = (const float*)d_in[14];
  float* out = (float*)d_out;
  float* ws  = (float*)d_ws;

  setup_kernel<<<(int)(WREP_ELEMS / 256), 256, 0, stream>>>(wgx, wgh, wix, wih,
                                                            wfx, wfh, wox, woh, ws);
  for (int t = 0; t < T; ++t)
    lstm_step<<<256, 256, 0, stream>>>(x, bg, bi, bf, bo, ws, t);

  // final h is in buffer (T & 1) = 0
  proj_kernel<<<B, H, 0, stream>>>(ws + HBUF_OFF, wph, bp, out);
}